// Round 4
// baseline (133.152 us; speedup 1.0000x reference)
//
#include <hip/hip_runtime.h>
#include <hip/hip_bf16.h>
#include <stdint.h>

typedef __bf16 bf16x8 __attribute__((ext_vector_type(8)));
typedef float  f32x4  __attribute__((ext_vector_type(4)));
typedef __attribute__((address_space(1))) uint32_t u32_g;
typedef __attribute__((address_space(3))) uint32_t u32_l;
typedef unsigned short u16;
typedef u16 u16x4 __attribute__((ext_vector_type(4)));

__device__ __forceinline__ void gload16(const void* g, void* l) {
    __builtin_amdgcn_global_load_lds((u32_g*)g, (u32_l*)l, 16, 0, 0);
}

__device__ __forceinline__ u16 bf16bits(float v) {
    __bf16 h = (__bf16)v;
    return __builtin_bit_cast(u16, h);
}

#define WAITV(n) asm volatile("s_waitcnt vmcnt(" #n ")" ::: "memory")
#define WAITLGKM0() do { asm volatile("s_waitcnt lgkmcnt(0)" ::: "memory"); \
                         __builtin_amdgcn_sched_barrier(0); } while (0)
#define BAR() do { __builtin_amdgcn_s_barrier(); \
                   __builtin_amdgcn_sched_barrier(0); } while (0)

// ---------------------------------------------------------------------------
// k_prep:
//   b <  512 : WT[z][kc'] = bf16(w_out[c*32+e][z]),  kc' = e*32 + c
//   b <  576 : WcatT[n][k] = bf16(n<32 ? w1[k][n] : w2[k][n-32])
//   else     : norm[i][j] = mask^T mask + 1e-3, one block per i
// ---------------------------------------------------------------------------
__global__ __launch_bounds__(256) void k_prep(const float* __restrict__ w_out,
                                              const float* __restrict__ mask,
                                              const float* __restrict__ w1,
                                              const float* __restrict__ w2,
                                              u16* __restrict__ WT,
                                              u16* __restrict__ WcatT,
                                              float* __restrict__ normv) {
    __shared__ float mcol[256];
    const int b = blockIdx.x, t = threadIdx.x;
    if (b < 512) {
        int idx = b * 256 + t;            // z*1024 + kc'
        int z = idx >> 10, kc = idx & 1023;
        int c = kc & 31, e = kc >> 5;
        WT[idx] = bf16bits(w_out[(c * 32 + e) * 128 + z]);
    } else if (b < 576) {
        int idx = (b - 512) * 256 + t;
        int n = idx >> 8, k = idx & 255;
        float v = (n < 32) ? w1[k * 32 + n] : w2[k * 32 + (n - 32)];
        WcatT[idx] = bf16bits(v);
    } else {
        int i = b - 576;
        mcol[t] = mask[(size_t)t * 256 + i];
        __syncthreads();
        float acc = 1e-3f;
#pragma unroll 8
        for (int s = 0; s < 256; ++s)
            acc += mcol[s] * mask[(size_t)s * 256 + t];
        normv[i * 256 + t] = acc;
    }
}

// ---------------------------------------------------------------------------
// k_lnproj: LayerNorm + dual projection via MFMA (unchanged).
// ---------------------------------------------------------------------------
__global__ __launch_bounds__(256, 2) void k_lnproj(
        const float* __restrict__ M, const float* __restrict__ mask,
        const float* __restrict__ lnw, const float* __restrict__ lnb,
        const float* __restrict__ b1, const float* __restrict__ b2,
        const u16* __restrict__ WcatT,
        u16* __restrict__ AT, u16* __restrict__ BT) {
    __shared__ __align__(16) u16 sh[32768];   // 64 KB
    const int tid = threadIdx.x, lane = tid & 63, w = tid >> 6;
    const int i = blockIdx.x, s0 = blockIdx.y * 64;

#pragma unroll
    for (int p = 0; p < 8; ++p) {
        int flat = p * 256 + tid;
        int r = flat >> 5, slot = flat & 31;
        int gs = slot ^ (r & 7);
        const char* src = (const char*)WcatT + (size_t)r * 512 + (size_t)gs * 16;
        char* dst = (char*)sh + 32768 + (size_t)(p * 256 + (tid & ~63)) * 16;
        gload16(src, dst);
    }

    float4 wv = *(const float4*)(lnw + lane * 4);
    float4 bv = *(const float4*)(lnb + lane * 4);
    float4 xv[16];
#pragma unroll
    for (int it = 0; it < 16; ++it) {
        int s = s0 + w * 16 + it;
        xv[it] = *(const float4*)(M + ((size_t)s * 256 + i) * 256 + lane * 4);
    }
#pragma unroll
    for (int it = 0; it < 16; ++it) {
        int row = w * 16 + it;
        float4 x = xv[it];
        float s1 = x.x + x.y + x.z + x.w;
        float s2 = x.x * x.x + x.y * x.y + x.z * x.z + x.w * x.w;
#pragma unroll
        for (int o = 1; o < 64; o <<= 1) {
            s1 += __shfl_xor(s1, o);
            s2 += __shfl_xor(s2, o);
        }
        float mu   = s1 * 0.00390625f;
        float var  = s2 * 0.00390625f - mu * mu;
        float rstd = rsqrtf(var + 1e-5f);
        u16x4 pk;
        pk[0] = bf16bits((x.x - mu) * rstd * wv.x + bv.x);
        pk[1] = bf16bits((x.y - mu) * rstd * wv.y + bv.y);
        pk[2] = bf16bits((x.z - mu) * rstd * wv.z + bv.z);
        pk[3] = bf16bits((x.w - mu) * rstd * wv.w + bv.w);
        int byte = (row * 512 + lane * 8) ^ ((row & 7) << 4);
        *(u16x4*)((char*)sh + byte) = pk;
    }
    __syncthreads();

    f32x4 acc[4] = {};
#pragma unroll
    for (int kk = 0; kk < 8; ++kk) {
        int kb = kk * 64 + ((lane >> 4) << 4);
        int arow = w * 16 + (lane & 15);
        bf16x8 af = *(const bf16x8*)((const char*)sh +
                     ((arow * 512 + kb) ^ ((arow & 7) << 4)));
#pragma unroll
        for (int f = 0; f < 4; ++f) {
            int nrow = f * 16 + (lane & 15);
            bf16x8 bfr = *(const bf16x8*)((const char*)sh + 32768 +
                          ((nrow * 512 + kb) ^ ((nrow & 7) << 4)));
            acc[f] = __builtin_amdgcn_mfma_f32_16x16x32_bf16(af, bfr, acc[f], 0, 0, 0);
        }
    }

    const int sb = s0 + w * 16 + ((lane >> 4) << 2);
    float mk[4];
#pragma unroll
    for (int r = 0; r < 4; ++r) mk[r] = mask[(size_t)(sb + r) * 256 + i];
#pragma unroll
    for (int f = 0; f < 4; ++f) {
        int col = f * 16 + (lane & 15);
        float bias = (col < 32) ? b1[col] : b2[col - 32];
        u16* dst = ((col < 32) ? AT : BT) + ((size_t)i * 32 + (col & 31)) * 256 + sb;
        u16x4 pk;
#pragma unroll
        for (int r = 0; r < 4; ++r)
            pk[r] = bf16bits((acc[f][r] + bias) * mk[r]);
        *(u16x4*)dst = pk;
    }
}

// ---------------------------------------------------------------------------
// k_fused: 256x256x256 GEMM1, 8-phase counted-vmcnt schedule + GEMM2 + epilogue.
// 8 waves (2 wr x 4 wc); wave frag (mh,mi,nh,nj):
//   m = mh*128 + wr*64 + mi*16 + ...,  n = nh*128 + wc*32 + nj*16 + ...
// LDS per buffer (64KB): Ah0@0, Ah1@16K, Bh0@32K, Bh1@48K; 2 buffers = 128KB.
// Stage unit = one half (16KB) = 2 gload16/thread. Phases (0,0),(1,0),(0,1),(1,1).
// ---------------------------------------------------------------------------
__global__ __launch_bounds__(512, 2) void k_fused(
        const u16* __restrict__ AT, const u16* __restrict__ BT,
        const u16* __restrict__ WT, const float* __restrict__ normv,
        const float* __restrict__ b_out, float* __restrict__ out) {
    __shared__ __align__(16) u16 sh[65536];   // 128 KB
    const int tid  = threadIdx.x;
    const int lane = tid & 63;
    const int wid  = tid >> 6;
    const int wr   = wid >> 2, wc = wid & 3;   // 2 x 4 wave grid
    const int l15  = lane & 15;
    const int kq   = (lane >> 4) << 4;         // 16B k-slot within row
    // XCD-bijective swizzle (nwg=1024, 8 XCDs, 128 blocks per XCD chunk)
    const int lid = blockIdx.x;
    const int swz = (lid & 7) * 128 + (lid >> 3);
    const int bx = swz & 31, by = swz >> 5;
    const int m0 = bx * 256, n0 = by * 256;

    f32x4 acc[8][4] = {};

    auto unit = [&](int kt, int which) {   // which: 0=Ah0 1=Ah1 2=Bh0 3=Bh1
        const int half = which & 1, isB = which >> 1;
        char* base = (char*)sh + (kt & 1) * 65536 + isB * 32768 + half * 16384;
        const u16* srcm = isB ? BT : AT;
        const int row0 = (isB ? n0 : m0) + half * 128;
        const int k0 = kt * 64;
#pragma unroll
        for (int q = 0; q < 2; ++q) {
            int flat = q * 512 + tid;
            int r = flat >> 3, slot = flat & 7;
            int gs = slot ^ (r & 7);
            gload16((const char*)srcm + (((size_t)(row0 + r)) * 256 + k0) * 2 + gs * 16,
                    base + (size_t)(q * 512 + (tid & ~63)) * 16);
        }
    };

#define PHASE(BUFC, MH, NH, STAGE_CODE, TAIL_CODE) do {                          \
    bf16x8 af_[4][2], bf_[2][2];                                                 \
    const char* Ab_ = (BUFC) + (MH) * 16384;                                     \
    const char* Bb_ = (BUFC) + 32768 + (NH) * 16384;                             \
    _Pragma("unroll") for (int mi = 0; mi < 4; ++mi)                             \
    _Pragma("unroll") for (int ks = 0; ks < 2; ++ks) {                           \
        int rA = wr * 64 + mi * 16 + l15;                                        \
        int kb = ks * 64 + kq;                                                   \
        af_[mi][ks] = *(const bf16x8*)(Ab_ + rA * 128 + (kb ^ ((rA & 7) << 4))); \
    }                                                                            \
    _Pragma("unroll") for (int nj = 0; nj < 2; ++nj)                             \
    _Pragma("unroll") for (int ks = 0; ks < 2; ++ks) {                           \
        int rB = wc * 32 + nj * 16 + l15;                                        \
        int kb = ks * 64 + kq;                                                   \
        bf_[nj][ks] = *(const bf16x8*)(Bb_ + rB * 128 + (kb ^ ((rB & 7) << 4))); \
    }                                                                            \
    STAGE_CODE;                                                                  \
    BAR();                                                                       \
    WAITLGKM0();                                                                 \
    __builtin_amdgcn_s_setprio(1);                                               \
    _Pragma("unroll") for (int mi = 0; mi < 4; ++mi)                             \
    _Pragma("unroll") for (int nj = 0; nj < 2; ++nj)                             \
    _Pragma("unroll") for (int ks = 0; ks < 2; ++ks)                             \
        acc[(MH)*4+mi][(NH)*2+nj] = __builtin_amdgcn_mfma_f32_16x16x32_bf16(     \
            af_[mi][ks], bf_[nj][ks], acc[(MH)*4+mi][(NH)*2+nj], 0, 0, 0);       \
    __builtin_amdgcn_s_setprio(0);                                               \
    TAIL_CODE;                                                                   \
    BAR();                                                                       \
} while (0)

    // ---- prologue: t0 all 4 units, t1 Ah0+Bh0
    unit(0, 0); unit(0, 1); unit(0, 2); unit(0, 3);
    unit(1, 0); unit(1, 2);
    WAITV(4);                              // t0 fully landed (t1's 4 loads outstanding)
    BAR();

    { const char* bufc = (const char*)sh;          // ---- tile 0 (buf0)
      PHASE(bufc, 0, 0, { unit(1, 1); unit(1, 3); }, {});
      PHASE(bufc, 1, 0, {}, {});
      PHASE(bufc, 0, 1, { unit(2, 2); }, {});
      PHASE(bufc, 1, 1, { unit(2, 0); }, { WAITV(4); });
    }
    { const char* bufc = (const char*)sh + 65536;  // ---- tile 1 (buf1)
      PHASE(bufc, 0, 0, { unit(2, 1); unit(2, 3); }, {});
      PHASE(bufc, 1, 0, {}, {});
      PHASE(bufc, 0, 1, { unit(3, 2); }, {});
      PHASE(bufc, 1, 1, { unit(3, 0); }, { WAITV(4); });
    }
    { const char* bufc = (const char*)sh;          // ---- tile 2 (buf0)
      PHASE(bufc, 0, 0, { unit(3, 1); unit(3, 3); }, {});
      PHASE(bufc, 1, 0, {}, {});
      PHASE(bufc, 0, 1, {}, {});
      PHASE(bufc, 1, 1, {}, { WAITV(0); });
    }
    { const char* bufc = (const char*)sh + 65536;  // ---- tile 3 (buf1)
      PHASE(bufc, 0, 0, {}, {});
      PHASE(bufc, 1, 0, {}, {});
      PHASE(bufc, 0, 1, {}, {});
      PHASE(bufc, 1, 1, {}, {});
    }
#undef PHASE

    // ---- write outer tile into P[64 pairs][1024] bf16 (kc' = e*32+c), swizzled.
#pragma unroll
    for (int mh = 0; mh < 2; ++mh)
#pragma unroll
    for (int mi = 0; mi < 4; ++mi)
#pragma unroll
    for (int nh = 0; nh < 2; ++nh)
#pragma unroll
    for (int nj = 0; nj < 2; ++nj) {
        int m = mh * 128 + wr * 64 + mi * 16 + ((lane >> 4) << 2);
        int n = nh * 128 + wc * 32 + nj * 16 + l15;
        int pr = ((m >> 5) << 3) | (n >> 5);
        int c0 = m & 31, e = n & 31;
        int byte = pr * 2048 + (e * 32 + c0) * 2;
        byte ^= ((pr ^ e) & 7) << 4;
        u16x4 pk;
#pragma unroll
        for (int r = 0; r < 4; ++r)
            pk[r] = bf16bits(acc[mh * 4 + mi][nh * 2 + nj][r]);
        *(u16x4*)((char*)sh + byte) = pk;
    }
    asm volatile("s_waitcnt lgkmcnt(0)" ::: "memory");
    BAR();

    // ---- GEMM2: [64 x 1024] @ WT^T[128 x 1024] -> [64 x 128]
    // wave (wr,wc): pairs [wr*32,+32), z in [wc*32,+32); 4-deep WT reg ring.
    f32x4 acc2[2][2] = {};
    const int prb = wr * 32 + l15;
    const int zb  = wc * 32 + l15;
    const int ko  = (lane >> 4) << 3;          // k offset (elements)
    bf16x8 wb[4][2];
#pragma unroll
    for (int d = 0; d < 3; ++d)
#pragma unroll
        for (int zf = 0; zf < 2; ++zf)
            wb[d][zf] = *(const bf16x8*)(WT + (size_t)(zb + zf * 16) * 1024 + d * 32 + ko);
#pragma unroll
    for (int ks = 0; ks < 32; ++ks) {
        if (ks + 3 < 32) {
#pragma unroll
            for (int zf = 0; zf < 2; ++zf)
                wb[(ks + 3) & 3][zf] = *(const bf16x8*)(WT +
                    (size_t)(zb + zf * 16) * 1024 + (ks + 3) * 32 + ko);
        }
        bf16x8 pa[2];
#pragma unroll
        for (int mf = 0; mf < 2; ++mf) {
            int pr = prb + mf * 16;
            int byte = pr * 2048 + (ks * 32 + ko) * 2;
            byte ^= ((pr ^ ks) & 7) << 4;
            pa[mf] = *(const bf16x8*)((const char*)sh + byte);
        }
        __builtin_amdgcn_s_setprio(1);
#pragma unroll
        for (int mf = 0; mf < 2; ++mf)
#pragma unroll
            for (int zf = 0; zf < 2; ++zf)
                acc2[mf][zf] = __builtin_amdgcn_mfma_f32_16x16x32_bf16(
                    pa[mf], wb[ks & 3][zf], acc2[mf][zf], 0, 0, 0);
        __builtin_amdgcn_s_setprio(0);
    }

    // ---- epilogue: + b_out, / norm, store f32 (lanes 0-15 -> consecutive z)
    const int i0 = bx * 8, j0 = by * 8;
#pragma unroll
    for (int mf = 0; mf < 2; ++mf)
#pragma unroll
        for (int zf = 0; zf < 2; ++zf)
#pragma unroll
            for (int r = 0; r < 4; ++r) {
                int pr = wr * 32 + mf * 16 + ((lane >> 4) << 2) + r;
                int z  = wc * 32 + zf * 16 + l15;
                int i = i0 + (pr >> 3), j = j0 + (pr & 7);
                float val = (acc2[mf][zf][r] + b_out[z]) / normv[i * 256 + j];
                out[((size_t)(i * 256 + j)) * 128 + z] = val;
            }
}

// ---------------------------------------------------------------------------
extern "C" void kernel_launch(void* const* d_in, const int* in_sizes, int n_in,
                              void* d_out, int out_size, void* d_ws, size_t ws_size,
                              hipStream_t stream) {
    const float* M    = (const float*)d_in[0];
    const float* mask = (const float*)d_in[1];
    const float* lnw  = (const float*)d_in[2];
    const float* lnb  = (const float*)d_in[3];
    const float* w1   = (const float*)d_in[4];
    const float* b1   = (const float*)d_in[5];
    const float* w2   = (const float*)d_in[6];
    const float* b2   = (const float*)d_in[7];
    const float* wout = (const float*)d_in[8];
    const float* bout = (const float*)d_in[9];
    float* out = (float*)d_out;

    char* ws = (char*)d_ws;
    u16*   AT    = (u16*)(ws);                 // [8192][256] bf16 = 4 MB
    u16*   BT    = (u16*)(ws + 4194304);       // 4 MB
    u16*   WT    = (u16*)(ws + 8388608);       // [128][1024] bf16 = 256 KB
    float* normv = (float*)(ws + 8650752);     // [256][256] f32 = 256 KB
    u16*   WcatT = (u16*)(ws + 8912896);       // [64][256] bf16 = 32 KB

    k_prep  <<<832, 256, 0, stream>>>(wout, mask, w1, w2, WT, WcatT, normv);
    k_lnproj<<<dim3(256, 4), 256, 0, stream>>>(M, mask, lnw, lnb, b1, b2, WcatT, AT, BT);
    k_fused <<<1024, 512, 0, stream>>>(AT, BT, WT, normv, bout, out);
}

// Round 5
// 120.968 us; speedup vs baseline: 1.1007x; 1.1007x over previous
//
#include <hip/hip_runtime.h>
#include <hip/hip_bf16.h>
#include <stdint.h>

typedef __bf16 bf16x8 __attribute__((ext_vector_type(8)));
typedef float  f32x4  __attribute__((ext_vector_type(4)));
typedef __attribute__((address_space(1))) uint32_t u32_g;
typedef __attribute__((address_space(3))) uint32_t u32_l;
typedef unsigned short u16;
typedef u16 u16x4 __attribute__((ext_vector_type(4)));

__device__ __forceinline__ void gload16(const void* g, void* l) {
    __builtin_amdgcn_global_load_lds((u32_g*)g, (u32_l*)l, 16, 0, 0);
}

__device__ __forceinline__ u16 bf16bits(float v) {
    __bf16 h = (__bf16)v;
    return __builtin_bit_cast(u16, h);
}

#define WAITV0() asm volatile("s_waitcnt vmcnt(0)" ::: "memory")
#define BAR() do { __builtin_amdgcn_s_barrier(); \
                   __builtin_amdgcn_sched_barrier(0); } while (0)

// ---------------------------------------------------------------------------
// k_prep:
//   b <  512 : WT[z][kc'] = bf16(w_out[c*32+e][z]),  kc' = e*32 + c
//   b <  576 : WcatT[n][k] = bf16(n<32 ? w1[k][n] : w2[k][n-32])
//   else     : norm[i][j] = mask^T mask + 1e-3, one block per i
// ---------------------------------------------------------------------------
__global__ __launch_bounds__(256) void k_prep(const float* __restrict__ w_out,
                                              const float* __restrict__ mask,
                                              const float* __restrict__ w1,
                                              const float* __restrict__ w2,
                                              u16* __restrict__ WT,
                                              u16* __restrict__ WcatT,
                                              float* __restrict__ normv) {
    __shared__ float mcol[256];
    const int b = blockIdx.x, t = threadIdx.x;
    if (b < 512) {
        int idx = b * 256 + t;            // z*1024 + kc'
        int z = idx >> 10, kc = idx & 1023;
        int c = kc & 31, e = kc >> 5;
        WT[idx] = bf16bits(w_out[(c * 32 + e) * 128 + z]);
    } else if (b < 576) {
        int idx = (b - 512) * 256 + t;
        int n = idx >> 8, k = idx & 255;
        float v = (n < 32) ? w1[k * 32 + n] : w2[k * 32 + (n - 32)];
        WcatT[idx] = bf16bits(v);
    } else {
        int i = b - 576;
        mcol[t] = mask[(size_t)t * 256 + i];
        __syncthreads();
        float acc = 1e-3f;
#pragma unroll 8
        for (int s = 0; s < 256; ++s)
            acc += mcol[s] * mask[(size_t)s * 256 + t];
        normv[i * 256 + t] = acc;
    }
}

// ---------------------------------------------------------------------------
// k_lnproj: LayerNorm + dual projection via MFMA (unchanged).
// ---------------------------------------------------------------------------
__global__ __launch_bounds__(256, 2) void k_lnproj(
        const float* __restrict__ M, const float* __restrict__ mask,
        const float* __restrict__ lnw, const float* __restrict__ lnb,
        const float* __restrict__ b1, const float* __restrict__ b2,
        const u16* __restrict__ WcatT,
        u16* __restrict__ AT, u16* __restrict__ BT) {
    __shared__ __align__(16) u16 sh[32768];   // 64 KB
    const int tid = threadIdx.x, lane = tid & 63, w = tid >> 6;
    const int i = blockIdx.x, s0 = blockIdx.y * 64;

#pragma unroll
    for (int p = 0; p < 8; ++p) {
        int flat = p * 256 + tid;
        int r = flat >> 5, slot = flat & 31;
        int gs = slot ^ (r & 7);
        const char* src = (const char*)WcatT + (size_t)r * 512 + (size_t)gs * 16;
        char* dst = (char*)sh + 32768 + (size_t)(p * 256 + (tid & ~63)) * 16;
        gload16(src, dst);
    }

    float4 wv = *(const float4*)(lnw + lane * 4);
    float4 bv = *(const float4*)(lnb + lane * 4);
    float4 xv[16];
#pragma unroll
    for (int it = 0; it < 16; ++it) {
        int s = s0 + w * 16 + it;
        xv[it] = *(const float4*)(M + ((size_t)s * 256 + i) * 256 + lane * 4);
    }
#pragma unroll
    for (int it = 0; it < 16; ++it) {
        int row = w * 16 + it;
        float4 x = xv[it];
        float s1 = x.x + x.y + x.z + x.w;
        float s2 = x.x * x.x + x.y * x.y + x.z * x.z + x.w * x.w;
#pragma unroll
        for (int o = 1; o < 64; o <<= 1) {
            s1 += __shfl_xor(s1, o);
            s2 += __shfl_xor(s2, o);
        }
        float mu   = s1 * 0.00390625f;
        float var  = s2 * 0.00390625f - mu * mu;
        float rstd = rsqrtf(var + 1e-5f);
        u16x4 pk;
        pk[0] = bf16bits((x.x - mu) * rstd * wv.x + bv.x);
        pk[1] = bf16bits((x.y - mu) * rstd * wv.y + bv.y);
        pk[2] = bf16bits((x.z - mu) * rstd * wv.z + bv.z);
        pk[3] = bf16bits((x.w - mu) * rstd * wv.w + bv.w);
        int byte = (row * 512 + lane * 8) ^ ((row & 7) << 4);
        *(u16x4*)((char*)sh + byte) = pk;
    }
    __syncthreads();

    f32x4 acc[4] = {};
#pragma unroll
    for (int kk = 0; kk < 8; ++kk) {
        int kb = kk * 64 + ((lane >> 4) << 4);
        int arow = w * 16 + (lane & 15);
        bf16x8 af = *(const bf16x8*)((const char*)sh +
                     ((arow * 512 + kb) ^ ((arow & 7) << 4)));
#pragma unroll
        for (int f = 0; f < 4; ++f) {
            int nrow = f * 16 + (lane & 15);
            bf16x8 bfr = *(const bf16x8*)((const char*)sh + 32768 +
                          ((nrow * 512 + kb) ^ ((nrow & 7) << 4)));
            acc[f] = __builtin_amdgcn_mfma_f32_16x16x32_bf16(af, bfr, acc[f], 0, 0, 0);
        }
    }

    const int sb = s0 + w * 16 + ((lane >> 4) << 2);
    float mk[4];
#pragma unroll
    for (int r = 0; r < 4; ++r) mk[r] = mask[(size_t)(sb + r) * 256 + i];
#pragma unroll
    for (int f = 0; f < 4; ++f) {
        int col = f * 16 + (lane & 15);
        float bias = (col < 32) ? b1[col] : b2[col - 32];
        u16* dst = ((col < 32) ? AT : BT) + ((size_t)i * 32 + (col & 31)) * 256 + sb;
        u16x4 pk;
#pragma unroll
        for (int r = 0; r < 4; ++r)
            pk[r] = bf16bits((acc[f][r] + bias) * mk[r]);
        *(u16x4*)dst = pk;
    }
}

// ---------------------------------------------------------------------------
// k_fused v5: 128x256x256 GEMM1 (8 waves, wave tile 64x64, BK=32) + GEMM2.
// grid 2048 (64 bx x 32 by): i in [bx*4,+4), j in [by*8,+8).
// LDS 64 KB total -> 2 blocks/CU. dbuf: buf b at b*24576 {A[128][32]@0 (8KB),
// B[256][32]@8192 (16KB)}. Row = 64 B -> quarter-wave k-offsets stagger banks:
// conflict-free, NO swizzle. P[32][1024] bf16 (64 KB) reuses all of LDS.
// ---------------------------------------------------------------------------
__global__ __launch_bounds__(512, 4) void k_fused(
        const u16* __restrict__ AT, const u16* __restrict__ BT,
        const u16* __restrict__ WT, const float* __restrict__ normv,
        const float* __restrict__ b_out, float* __restrict__ out) {
    __shared__ __align__(16) u16 sh[32768];   // 64 KB
    const int tid  = threadIdx.x;
    const int lane = tid & 63;
    const int wid  = tid >> 6;
    const int wr   = wid >> 2, wc = wid & 3;   // GEMM1: 2 x 4 wave grid
    const int l15  = lane & 15;
    const int q16  = lane >> 4;
    // XCD swizzle: 2048 blocks, 256 per XCD chunk
    const int lid = blockIdx.x;
    const int swz = (lid & 7) * 256 + (lid >> 3);
    const int bx = swz & 63, by = swz >> 6;
    const int m0 = bx * 128, n0 = by * 256;

    f32x4 acc[4][4] = {};

    auto stage = [&](int kt, int buf) {
        char* base = (char*)sh + buf * 24576;
        const int k0 = kt * 32;
        // A[128][32]: 512 16B-chunks, r = tid>>2, slot = tid&3
        gload16((const char*)AT + (((size_t)(m0 + (tid >> 2))) * 256 + k0) * 2 + (tid & 3) * 16,
                base + (size_t)tid * 16);
        // B[256][32]: 1024 chunks
#pragma unroll
        for (int q = 0; q < 2; ++q) {
            int flat = q * 512 + tid;
            int r = flat >> 2, slot = flat & 3;
            gload16((const char*)BT + (((size_t)(n0 + r)) * 256 + k0) * 2 + slot * 16,
                    base + 8192 + (size_t)(q * 512 + (tid & ~63)) * 16);
        }
    };

    auto compute = [&](int buf) {
        const char* Ab = (const char*)sh + buf * 24576;
        const char* Bb = Ab + 8192;
        bf16x8 af[4], bfr[4];
#pragma unroll
        for (int mi = 0; mi < 4; ++mi) {
            int rA = wr * 64 + mi * 16 + l15;
            af[mi] = *(const bf16x8*)(Ab + rA * 64 + q16 * 16);
        }
#pragma unroll
        for (int nj = 0; nj < 4; ++nj) {
            int rB = wc * 64 + nj * 16 + l15;
            bfr[nj] = *(const bf16x8*)(Bb + rB * 64 + q16 * 16);
        }
        __builtin_amdgcn_s_setprio(1);
#pragma unroll
        for (int mi = 0; mi < 4; ++mi)
#pragma unroll
            for (int nj = 0; nj < 4; ++nj)
                acc[mi][nj] = __builtin_amdgcn_mfma_f32_16x16x32_bf16(
                    af[mi], bfr[nj], acc[mi][nj], 0, 0, 0);
        __builtin_amdgcn_s_setprio(0);
    };

    stage(0, 0);
    WAITV0();
    BAR();
#pragma unroll
    for (int t = 0; t < 8; ++t) {
        if (t < 7) stage(t + 1, (t + 1) & 1);
        compute(t & 1);
        if (t < 7) WAITV0();
        BAR();
    }

    // ---- write outer tile into P[32 pairs][1024] bf16 (kc' = e*32+c), swizzled.
    // m = wr*64+mi*16+q16*4+r (i_loc = m>>5, c = m&31); n = wc*64+nj*16+l15.
#pragma unroll
    for (int mi = 0; mi < 4; ++mi)
#pragma unroll
        for (int nj = 0; nj < 4; ++nj) {
            int m = wr * 64 + mi * 16 + (q16 << 2);
            int n = wc * 64 + nj * 16 + l15;
            int pr = ((m >> 5) << 3) | (n >> 5);
            int c0 = m & 31, e = n & 31;
            int byte = pr * 2048 + (e * 32 + c0) * 2;
            byte ^= ((pr ^ e) & 7) << 4;
            u16x4 pk;
#pragma unroll
            for (int r = 0; r < 4; ++r)
                pk[r] = bf16bits(acc[mi][nj][r]);
            *(u16x4*)((char*)sh + byte) = pk;
        }
    __syncthreads();

    // ---- GEMM2: P[32 x 1024] @ WT^T[128 x 1024] -> [32 x 128]
    // wave wid: z in [wid*16, +16); 2 pair-frags; 4-deep WT ring, 1-ahead pa.
    f32x4 acc2[2][2] = {};            // [pf][ks parity]
    const int zb = wid * 16 + l15;
    const int ko = q16 * 8;           // k element offset within 32-wide slab
    bf16x8 wbr[4];
    bf16x8 par[2][2];                 // [parity][pf]
#pragma unroll
    for (int d = 0; d < 3; ++d)
        wbr[d] = *(const bf16x8*)(WT + (size_t)zb * 1024 + d * 32 + ko);
#pragma unroll
    for (int pf = 0; pf < 2; ++pf) {
        int prw = pf * 16 + l15;
        int byte = (prw * 2048 + ko * 2) ^ ((prw & 7) << 4);   // ks=0
        par[0][pf] = *(const bf16x8*)((const char*)sh + byte);
    }
#pragma unroll
    for (int ks = 0; ks < 32; ++ks) {
        if (ks + 3 < 32)
            wbr[(ks + 3) & 3] = *(const bf16x8*)(WT + (size_t)zb * 1024 + (ks + 3) * 32 + ko);
        if (ks + 1 < 32) {
#pragma unroll
            for (int pf = 0; pf < 2; ++pf) {
                int prw = pf * 16 + l15;
                int byte = (prw * 2048 + ((ks + 1) * 32 + ko) * 2)
                           ^ (((prw ^ (ks + 1)) & 7) << 4);
                par[(ks + 1) & 1][pf] = *(const bf16x8*)((const char*)sh + byte);
            }
        }
        __builtin_amdgcn_s_setprio(1);
#pragma unroll
        for (int pf = 0; pf < 2; ++pf)
            acc2[pf][ks & 1] = __builtin_amdgcn_mfma_f32_16x16x32_bf16(
                par[ks & 1][pf], wbr[ks & 3], acc2[pf][ks & 1], 0, 0, 0);
        __builtin_amdgcn_s_setprio(0);
    }

    // ---- epilogue: + b_out, / norm, store f32
    const int i0 = bx * 4, j0 = by * 8;
#pragma unroll
    for (int pf = 0; pf < 2; ++pf)
#pragma unroll
        for (int r = 0; r < 4; ++r) {
            int pr = pf * 16 + (q16 << 2) + r;
            int z  = zb;                       // wid*16 + l15
            int i = i0 + (pr >> 3), j = j0 + (pr & 7);
            float val = (acc2[pf][0][r] + acc2[pf][1][r] + b_out[z]) / normv[i * 256 + j];
            out[((size_t)(i * 256 + j)) * 128 + z] = val;
        }
}

// ---------------------------------------------------------------------------
extern "C" void kernel_launch(void* const* d_in, const int* in_sizes, int n_in,
                              void* d_out, int out_size, void* d_ws, size_t ws_size,
                              hipStream_t stream) {
    const float* M    = (const float*)d_in[0];
    const float* mask = (const float*)d_in[1];
    const float* lnw  = (const float*)d_in[2];
    const float* lnb  = (const float*)d_in[3];
    const float* w1   = (const float*)d_in[4];
    const float* b1   = (const float*)d_in[5];
    const float* w2   = (const float*)d_in[6];
    const float* b2   = (const float*)d_in[7];
    const float* wout = (const float*)d_in[8];
    const float* bout = (const float*)d_in[9];
    float* out = (float*)d_out;

    char* ws = (char*)d_ws;
    u16*   AT    = (u16*)(ws);                 // [8192][256] bf16 = 4 MB
    u16*   BT    = (u16*)(ws + 4194304);       // 4 MB
    u16*   WT    = (u16*)(ws + 8388608);       // [128][1024] bf16 = 256 KB
    float* normv = (float*)(ws + 8650752);     // [256][256] f32 = 256 KB
    u16*   WcatT = (u16*)(ws + 8912896);       // [64][256] bf16 = 32 KB

    k_prep  <<<832, 256, 0, stream>>>(wout, mask, w1, w2, WT, WcatT, normv);
    k_lnproj<<<dim3(256, 4), 256, 0, stream>>>(M, mask, lnw, lnb, b1, b2, WcatT, AT, BT);
    k_fused <<<2048, 512, 0, stream>>>(AT, BT, WT, normv, bout, out);
}

// Round 6
// 117.282 us; speedup vs baseline: 1.1353x; 1.0314x over previous
//
#include <hip/hip_runtime.h>
#include <hip/hip_bf16.h>
#include <stdint.h>

typedef __bf16 bf16x8 __attribute__((ext_vector_type(8)));
typedef float  f32x4  __attribute__((ext_vector_type(4)));
typedef __attribute__((address_space(1))) uint32_t u32_g;
typedef __attribute__((address_space(3))) uint32_t u32_l;
typedef unsigned short u16;
typedef u16 u16x4 __attribute__((ext_vector_type(4)));

__device__ __forceinline__ void gload16(const void* g, void* l) {
    __builtin_amdgcn_global_load_lds((u32_g*)g, (u32_l*)l, 16, 0, 0);
}

__device__ __forceinline__ u16 bf16bits(float v) {
    __bf16 h = (__bf16)v;
    return __builtin_bit_cast(u16, h);
}

#define WAITV(n) asm volatile("s_waitcnt vmcnt(" #n ")" ::: "memory")
#define BAR() do { __builtin_amdgcn_s_barrier(); \
                   __builtin_amdgcn_sched_barrier(0); } while (0)

// ---------------------------------------------------------------------------
// k_prep:
//   b <  512 : WT[z][kc'] = bf16(w_out[c*32+e][z]),  kc' = e*32 + c
//   b <  576 : WcatT[n][k] = bf16(n<32 ? w1[k][n] : w2[k][n-32])
//   else     : norm[i][j] = mask^T mask + 1e-3, one block per i
// ---------------------------------------------------------------------------
__global__ __launch_bounds__(256) void k_prep(const float* __restrict__ w_out,
                                              const float* __restrict__ mask,
                                              const float* __restrict__ w1,
                                              const float* __restrict__ w2,
                                              u16* __restrict__ WT,
                                              u16* __restrict__ WcatT,
                                              float* __restrict__ normv) {
    __shared__ float mcol[256];
    const int b = blockIdx.x, t = threadIdx.x;
    if (b < 512) {
        int idx = b * 256 + t;            // z*1024 + kc'
        int z = idx >> 10, kc = idx & 1023;
        int c = kc & 31, e = kc >> 5;
        WT[idx] = bf16bits(w_out[(c * 32 + e) * 128 + z]);
    } else if (b < 576) {
        int idx = (b - 512) * 256 + t;
        int n = idx >> 8, k = idx & 255;
        float v = (n < 32) ? w1[k * 32 + n] : w2[k * 32 + (n - 32)];
        WcatT[idx] = bf16bits(v);
    } else {
        int i = b - 576;
        mcol[t] = mask[(size_t)t * 256 + i];
        __syncthreads();
        float acc = 1e-3f;
#pragma unroll 8
        for (int s = 0; s < 256; ++s)
            acc += mcol[s] * mask[(size_t)s * 256 + t];
        normv[i * 256 + t] = acc;
    }
}

// ---------------------------------------------------------------------------
// k_lnproj: LayerNorm + dual projection via MFMA (unchanged).
// ---------------------------------------------------------------------------
__global__ __launch_bounds__(256, 2) void k_lnproj(
        const float* __restrict__ M, const float* __restrict__ mask,
        const float* __restrict__ lnw, const float* __restrict__ lnb,
        const float* __restrict__ b1, const float* __restrict__ b2,
        const u16* __restrict__ WcatT,
        u16* __restrict__ AT, u16* __restrict__ BT) {
    __shared__ __align__(16) u16 sh[32768];   // 64 KB
    const int tid = threadIdx.x, lane = tid & 63, w = tid >> 6;
    const int i = blockIdx.x, s0 = blockIdx.y * 64;

#pragma unroll
    for (int p = 0; p < 8; ++p) {
        int flat = p * 256 + tid;
        int r = flat >> 5, slot = flat & 31;
        int gs = slot ^ (r & 7);
        const char* src = (const char*)WcatT + (size_t)r * 512 + (size_t)gs * 16;
        char* dst = (char*)sh + 32768 + (size_t)(p * 256 + (tid & ~63)) * 16;
        gload16(src, dst);
    }

    float4 wv = *(const float4*)(lnw + lane * 4);
    float4 bv = *(const float4*)(lnb + lane * 4);
    float4 xv[16];
#pragma unroll
    for (int it = 0; it < 16; ++it) {
        int s = s0 + w * 16 + it;
        xv[it] = *(const float4*)(M + ((size_t)s * 256 + i) * 256 + lane * 4);
    }
#pragma unroll
    for (int it = 0; it < 16; ++it) {
        int row = w * 16 + it;
        float4 x = xv[it];
        float s1 = x.x + x.y + x.z + x.w;
        float s2 = x.x * x.x + x.y * x.y + x.z * x.z + x.w * x.w;
#pragma unroll
        for (int o = 1; o < 64; o <<= 1) {
            s1 += __shfl_xor(s1, o);
            s2 += __shfl_xor(s2, o);
        }
        float mu   = s1 * 0.00390625f;
        float var  = s2 * 0.00390625f - mu * mu;
        float rstd = rsqrtf(var + 1e-5f);
        u16x4 pk;
        pk[0] = bf16bits((x.x - mu) * rstd * wv.x + bv.x);
        pk[1] = bf16bits((x.y - mu) * rstd * wv.y + bv.y);
        pk[2] = bf16bits((x.z - mu) * rstd * wv.z + bv.z);
        pk[3] = bf16bits((x.w - mu) * rstd * wv.w + bv.w);
        int byte = (row * 512 + lane * 8) ^ ((row & 7) << 4);
        *(u16x4*)((char*)sh + byte) = pk;
    }
    __syncthreads();

    f32x4 acc[4] = {};
#pragma unroll
    for (int kk = 0; kk < 8; ++kk) {
        int kb = kk * 64 + ((lane >> 4) << 4);
        int arow = w * 16 + (lane & 15);
        bf16x8 af = *(const bf16x8*)((const char*)sh +
                     ((arow * 512 + kb) ^ ((arow & 7) << 4)));
#pragma unroll
        for (int f = 0; f < 4; ++f) {
            int nrow = f * 16 + (lane & 15);
            bf16x8 bfr = *(const bf16x8*)((const char*)sh + 32768 +
                          ((nrow * 512 + kb) ^ ((nrow & 7) << 4)));
            acc[f] = __builtin_amdgcn_mfma_f32_16x16x32_bf16(af, bfr, acc[f], 0, 0, 0);
        }
    }

    const int sb = s0 + w * 16 + ((lane >> 4) << 2);
    float mk[4];
#pragma unroll
    for (int r = 0; r < 4; ++r) mk[r] = mask[(size_t)(sb + r) * 256 + i];
#pragma unroll
    for (int f = 0; f < 4; ++f) {
        int col = f * 16 + (lane & 15);
        float bias = (col < 32) ? b1[col] : b2[col - 32];
        u16* dst = ((col < 32) ? AT : BT) + ((size_t)i * 32 + (col & 31)) * 256 + sb;
        u16x4 pk;
#pragma unroll
        for (int r = 0; r < 4; ++r)
            pk[r] = bf16bits((acc[f][r] + bias) * mk[r]);
        *(u16x4*)dst = pk;
    }
}

// ---------------------------------------------------------------------------
// k_fused v6: 128x256x256 GEMM1 (8 waves, wave tile 64x64, BK=32) + GEMM2.
// grid 2048 (64 bx x 32 by): i in [bx*4,+4), j in [by*8,+8).
// 3 LDS buffers x 24KB (A[128][32]@0, B[256][32]@8192), depth-2 prefetch,
// counted vmcnt(3). Row = 64B; slot swizzle s^=(row>>1)&3 -> 2-way (free).
// P[32][1024] bf16 (64 KB) reuses bufs. LDS 72KB -> 2 blocks/CU.
// ---------------------------------------------------------------------------
__global__ __launch_bounds__(512, 4) void k_fused(
        const u16* __restrict__ AT, const u16* __restrict__ BT,
        const u16* __restrict__ WT, const float* __restrict__ normv,
        const float* __restrict__ b_out, float* __restrict__ out) {
    __shared__ __align__(16) u16 sh[36864];   // 72 KB
    const int tid  = threadIdx.x;
    const int lane = tid & 63;
    const int wid  = tid >> 6;
    const int wr   = wid >> 2, wc = wid & 3;   // GEMM1: 2 x 4 wave grid
    const int l15  = lane & 15;
    const int q16  = lane >> 4;
    // XCD swizzle: 2048 blocks, 256 per XCD chunk
    const int lid = blockIdx.x;
    const int swz = (lid & 7) * 256 + (lid >> 3);
    const int bx = swz & 63, by = swz >> 6;
    const int m0 = bx * 128, n0 = by * 256;

    f32x4 acc[4][4] = {};

    auto stage = [&](int kt, int buf) {
        char* base = (char*)sh + buf * 24576;
        const int k0 = kt * 32;
        // A[128][32]: 512 16B-chunks; r = tid>>2, slot = tid&3, swizzled source
        {
            int r = tid >> 2, slot = tid & 3;
            int gs = slot ^ ((r >> 1) & 3);
            gload16((const char*)AT + (((size_t)(m0 + r)) * 256 + k0) * 2 + gs * 16,
                    base + (size_t)(tid & ~63) * 16);
        }
        // B[256][32]: 1024 chunks
#pragma unroll
        for (int q = 0; q < 2; ++q) {
            int flat = q * 512 + tid;
            int r = flat >> 2, slot = flat & 3;
            int gs = slot ^ ((r >> 1) & 3);
            gload16((const char*)BT + (((size_t)(n0 + r)) * 256 + k0) * 2 + gs * 16,
                    base + 8192 + (size_t)(q * 512 + (tid & ~63)) * 16);
        }
    };

    auto compute = [&](int buf) {
        const char* Ab = (const char*)sh + buf * 24576;
        const char* Bb = Ab + 8192;
        bf16x8 af[4], bfr[4];
#pragma unroll
        for (int mi = 0; mi < 4; ++mi) {
            int rA = wr * 64 + mi * 16 + l15;
            af[mi] = *(const bf16x8*)(Ab + rA * 64 + (q16 ^ ((rA >> 1) & 3)) * 16);
        }
#pragma unroll
        for (int nj = 0; nj < 4; ++nj) {
            int rB = wc * 64 + nj * 16 + l15;
            bfr[nj] = *(const bf16x8*)(Bb + rB * 64 + (q16 ^ ((rB >> 1) & 3)) * 16);
        }
        __builtin_amdgcn_s_setprio(1);
#pragma unroll
        for (int mi = 0; mi < 4; ++mi)
#pragma unroll
            for (int nj = 0; nj < 4; ++nj)
                acc[mi][nj] = __builtin_amdgcn_mfma_f32_16x16x32_bf16(
                    af[mi], bfr[nj], acc[mi][nj], 0, 0, 0);
        __builtin_amdgcn_s_setprio(0);
    };

    // prologue: tiles 0,1 in flight; wait tile0 (tile1's 3 loads outstanding)
    stage(0, 0);
    stage(1, 1);
    WAITV(3);
    BAR();
#pragma unroll
    for (int t = 0; t < 8; ++t) {
        if (t + 2 < 8) stage(t + 2, (t + 2) % 3);
        compute(t % 3);
        if (t < 6) { WAITV(3); }          // tile t+1 landed; t+2 stays in flight
        else if (t == 6) { WAITV(0); }    // tile 7 landed
        BAR();
    }

    // ---- write outer tile into P[32 pairs][1024] bf16 (kc' = e*32+c), swizzled.
    // m = wr*64+mi*16+q16*4+r (i_loc = m>>5, c = m&31); n = wc*64+nj*16+l15.
#pragma unroll
    for (int mi = 0; mi < 4; ++mi)
#pragma unroll
        for (int nj = 0; nj < 4; ++nj) {
            int m = wr * 64 + mi * 16 + (q16 << 2);
            int n = wc * 64 + nj * 16 + l15;
            int pr = ((m >> 5) << 3) | (n >> 5);
            int c0 = m & 31, e = n & 31;
            int byte = pr * 2048 + (e * 32 + c0) * 2;
            byte ^= ((pr ^ e) & 7) << 4;
            u16x4 pk;
#pragma unroll
            for (int r = 0; r < 4; ++r)
                pk[r] = bf16bits(acc[mi][nj][r]);
            *(u16x4*)((char*)sh + byte) = pk;
        }
    __syncthreads();

    // ---- GEMM2: P[32 x 1024] @ WT^T[128 x 1024] -> [32 x 128]
    // wave wid: z in [wid*16, +16); 2 pair-frags; 4-deep WT ring, 1-ahead pa.
    f32x4 acc2[2][2] = {};            // [pf][ks parity]
    const int zb = wid * 16 + l15;
    const int ko = q16 * 8;           // k element offset within 32-wide slab
    bf16x8 wbr[4];
    bf16x8 par[2][2];                 // [parity][pf]
#pragma unroll
    for (int d = 0; d < 3; ++d)
        wbr[d] = *(const bf16x8*)(WT + (size_t)zb * 1024 + d * 32 + ko);
#pragma unroll
    for (int pf = 0; pf < 2; ++pf) {
        int prw = pf * 16 + l15;
        int byte = (prw * 2048 + ko * 2) ^ ((prw & 7) << 4);   // ks=0
        par[0][pf] = *(const bf16x8*)((const char*)sh + byte);
    }
#pragma unroll
    for (int ks = 0; ks < 32; ++ks) {
        if (ks + 3 < 32)
            wbr[(ks + 3) & 3] = *(const bf16x8*)(WT + (size_t)zb * 1024 + (ks + 3) * 32 + ko);
        if (ks + 1 < 32) {
#pragma unroll
            for (int pf = 0; pf < 2; ++pf) {
                int prw = pf * 16 + l15;
                int byte = (prw * 2048 + ((ks + 1) * 32 + ko) * 2)
                           ^ (((prw ^ (ks + 1)) & 7) << 4);
                par[(ks + 1) & 1][pf] = *(const bf16x8*)((const char*)sh + byte);
            }
        }
        __builtin_amdgcn_s_setprio(1);
#pragma unroll
        for (int pf = 0; pf < 2; ++pf)
            acc2[pf][ks & 1] = __builtin_amdgcn_mfma_f32_16x16x32_bf16(
                par[ks & 1][pf], wbr[ks & 3], acc2[pf][ks & 1], 0, 0, 0);
        __builtin_amdgcn_s_setprio(0);
    }

    // ---- epilogue: + b_out, / norm, store f32
    const int i0 = bx * 4, j0 = by * 8;
#pragma unroll
    for (int pf = 0; pf < 2; ++pf)
#pragma unroll
        for (int r = 0; r < 4; ++r) {
            int pr = pf * 16 + (q16 << 2) + r;
            int z  = zb;                       // wid*16 + l15
            int i = i0 + (pr >> 3), j = j0 + (pr & 7);
            float val = (acc2[pf][0][r] + acc2[pf][1][r] + b_out[z]) / normv[i * 256 + j];
            out[((size_t)(i * 256 + j)) * 128 + z] = val;
        }
}

// ---------------------------------------------------------------------------
extern "C" void kernel_launch(void* const* d_in, const int* in_sizes, int n_in,
                              void* d_out, int out_size, void* d_ws, size_t ws_size,
                              hipStream_t stream) {
    const float* M    = (const float*)d_in[0];
    const float* mask = (const float*)d_in[1];
    const float* lnw  = (const float*)d_in[2];
    const float* lnb  = (const float*)d_in[3];
    const float* w1   = (const float*)d_in[4];
    const float* b1   = (const float*)d_in[5];
    const float* w2   = (const float*)d_in[6];
    const float* b2   = (const float*)d_in[7];
    const float* wout = (const float*)d_in[8];
    const float* bout = (const float*)d_in[9];
    float* out = (float*)d_out;

    char* ws = (char*)d_ws;
    u16*   AT    = (u16*)(ws);                 // [8192][256] bf16 = 4 MB
    u16*   BT    = (u16*)(ws + 4194304);       // 4 MB
    u16*   WT    = (u16*)(ws + 8388608);       // [128][1024] bf16 = 256 KB
    float* normv = (float*)(ws + 8650752);     // [256][256] f32 = 256 KB
    u16*   WcatT = (u16*)(ws + 8912896);       // [64][256] bf16 = 32 KB

    k_prep  <<<832, 256, 0, stream>>>(wout, mask, w1, w2, WT, WcatT, normv);
    k_lnproj<<<dim3(256, 4), 256, 0, stream>>>(M, mask, lnw, lnb, b1, b2, WcatT, AT, BT);
    k_fused <<<2048, 512, 0, stream>>>(AT, BT, WT, normv, bout, out);
}